// Round 8
// baseline (1132.856 us; speedup 1.0000x reference)
//
#include <hip/hip_runtime.h>
#include <hip/hip_bf16.h>
#include <stdint.h>

#define E_N 150000
#define IN 512
#define MAXLEN 240

// pair-class perm: 32 classes (tau*8+etype), each base 128-aligned
#define PPERM 154112          // >= E + 32*127, multiple of 128
#define NTILE2 1204           // PPERM/128 row-tiles
#define GRID_GEMM (NTILE2 * 8)

typedef __attribute__((ext_vector_type(8))) short short8;
typedef __attribute__((ext_vector_type(4))) float f32x4;

// ---------- ws layout (bytes) ----------
#define OFF_RB   0UL            // bf16 [240][512]        245760
#define OFF_W2   245760UL       // bf16 [32][1024][512]   33554432
#define OFF_B2   33800192UL     // f32  [32][1024]        131072
#define OFF_RW   33931264UL     // f32  [32][240][1024]   31457280
#define OFF_CNT  65388544UL     // int  [128]             512
#define OFF_PERM 65389056UL     // int  [PPERM]           616448
// total ~66 MB

static __device__ __forceinline__ short f2bf(float f) {
  union { float f; uint32_t u; } v; v.f = f;
  uint32_t u = v.u;
  uint32_t r = (u + 0x7fffu + ((u >> 16) & 1u)) >> 16;
  return (short)r;
}

static __device__ __forceinline__ uint32_t pk2(float a, float b) {
  union { __hip_bfloat162 h; uint32_t u; } v;
  v.h = __float22bfloat162_rn(make_float2(a, b));
  return v.u;
}

// R table in bf16: Rbf[p][o] = bf16(sum_i emb[p][i]*linW[o][i] + linB[o])
__global__ __launch_bounds__(256) void k_rte(const float* __restrict__ emb,
    const float* __restrict__ linW, const float* __restrict__ linB,
    short* __restrict__ Rbf) {
  __shared__ float x[IN];
  int p = blockIdx.x;
  for (int i = threadIdx.x; i < IN; i += 256) x[i] = emb[p * IN + i];
  __syncthreads();
  for (int o = threadIdx.x; o < IN; o += 256) {
    const float* w = linW + (long)o * IN;
    float s = 0.f;
#pragma unroll 4
    for (int k = 0; k < IN; k += 4) {
      float4 wv = *(const float4*)(w + k);
      s += wv.x * x[k] + wv.y * x[k + 1] + wv.z * x[k + 2] + wv.w * x[k + 3];
    }
    Rbf[p * IN + o] = f2bf(s + linB[o]);
  }
}

// Pair weights: W2[p=t*8+g][o][i] bf16, B2[p][o] f32.
// grid 2048 = 32 pairs x 16 (8 K-heads + 8 V-heads) x 4 i-quarters
__global__ __launch_bounds__(256) void k_wpair(
    const float* __restrict__ WattW, const float* __restrict__ WmsgW,
    const float* __restrict__ KW, const float* __restrict__ VW,
    const float* __restrict__ Kb, const float* __restrict__ Vb,
    short* __restrict__ W2, float* __restrict__ B2) {
  __shared__ float Tl[64][65];
  int blk = blockIdx.x;
  int p = blk >> 6, s = (blk >> 2) & 15, q = blk & 3;
  int t = p >> 3, g = p & 7;
  bool kside = s < 8;
  int h = kside ? s : s - 8;
  const float* T = (kside ? WattW : WmsgW) + (size_t)g * 4096;
  const float* S = (kside ? KW : VW) + ((size_t)t * 512 + h * 64) * 512;
  const float* bsrc = (kside ? Kb : Vb) + t * 512 + h * 64;
  int tid = threadIdx.x;
  for (int i = tid; i < 4096; i += 256) Tl[i >> 6][i & 63] = T[i];
  __syncthreads();
  int op = tid & 63, iq = tid >> 6;
  size_t obase = ((size_t)p * 1024 + (kside ? 0 : 512) + h * 64 + op) * 512;
  for (int i8 = q * 4; i8 < q * 4 + 4; i8++) {
    int i0 = iq * 128 + i8 * 8;
    float a0 = 0, a1 = 0, a2 = 0, a3 = 0, a4 = 0, a5 = 0, a6 = 0, a7 = 0;
    const float* sp0 = S + i0;
#pragma unroll 8
    for (int j = 0; j < 64; j++) {
      float tv = Tl[op][j];
      const float* sp = sp0 + j * 512;
      float4 s0 = *(const float4*)sp;
      float4 s1 = *(const float4*)(sp + 4);
      a0 += tv * s0.x; a1 += tv * s0.y; a2 += tv * s0.z; a3 += tv * s0.w;
      a4 += tv * s1.x; a5 += tv * s1.y; a6 += tv * s1.z; a7 += tv * s1.w;
    }
    short8 o8;
    o8[0] = f2bf(a0); o8[1] = f2bf(a1); o8[2] = f2bf(a2); o8[3] = f2bf(a3);
    o8[4] = f2bf(a4); o8[5] = f2bf(a5); o8[6] = f2bf(a6); o8[7] = f2bf(a7);
    *(short8*)(W2 + obase + i0) = o8;
  }
  if (q == 0 && tid < 64) {
    float b = 0;
#pragma unroll 8
    for (int j = 0; j < 64; j++) b += Tl[tid][j] * bsrc[j];
    B2[p * 1024 + (kside ? 0 : 512) + h * 64 + tid] = b;
  }
}

// RW2'[p][d][o] = sum_i Rbf[d][i]*W2[p][o][i] + B2[p][o]   (f32)
__global__ __launch_bounds__(256, 4) void k_rw2(
    const short* __restrict__ Rbf, const short* __restrict__ W2,
    const float* __restrict__ B2, float* __restrict__ RW) {
  __shared__ short sA[4096];
  __shared__ short sB[4096];
  int tid = threadIdx.x;
  int bid = blockIdx.x;
  int p = bid >> 4, rt = (bid >> 3) & 1, ctile = bid & 7;
  int n0 = ctile * 128;
  int r0 = rt * 128;

  int lane = tid & 63, w = tid >> 6, wm = w >> 1, wn = w & 1;

  int rS = w * 32 + (lane >> 2);
  int cS = lane & 3;
  int ch0 = (cS - (rS >> 1)) & 3;
  int ch1 = (cS - ((rS + 16) >> 1)) & 3;
  const char* rbb = (const char*)Rbf;
  const char* srcA0 = rbb + (size_t)(r0 + rS) * 1024 + ch0 * 16;
  const char* srcA1 = rbb + (size_t)(r0 + rS + 16) * 1024 + ch1 * 16;
  const char* wcb = (const char*)(W2 + ((size_t)p * 1024 + n0) * 512);
  const char* srcB0 = wcb + (size_t)rS * 1024 + ch0 * 16;
  const char* srcB1 = wcb + (size_t)(rS + 16) * 1024 + ch1 * 16;
  char* dA0 = (char*)sA + w * 2048;
  char* dA1 = (char*)sA + w * 2048 + 1024;
  char* dB0 = (char*)sB + w * 2048;
  char* dB1 = (char*)sB + w * 2048 + 1024;

  int aRow = wm * 64 + (lane & 15);
  int aOff = aRow * 64 + ((((lane >> 4) + (aRow >> 1)) & 3) << 4);
  int bRow = wn * 64 + (lane & 15);
  int bOff = bRow * 64 + ((((lane >> 4) + (bRow >> 1)) & 3) << 4);

  f32x4 acc[4][4] = {};
#pragma unroll
  for (int kk = 0; kk < 16; kk++) {
    __syncthreads();
    __builtin_amdgcn_global_load_lds((const uint32_t*)(srcA0 + kk * 64), (uint32_t*)dA0, 16, 0, 0);
    __builtin_amdgcn_global_load_lds((const uint32_t*)(srcA1 + kk * 64), (uint32_t*)dA1, 16, 0, 0);
    __builtin_amdgcn_global_load_lds((const uint32_t*)(srcB0 + kk * 64), (uint32_t*)dB0, 16, 0, 0);
    __builtin_amdgcn_global_load_lds((const uint32_t*)(srcB1 + kk * 64), (uint32_t*)dB1, 16, 0, 0);
    __syncthreads();
    short8 a[4], b[4];
#pragma unroll
    for (int mi = 0; mi < 4; mi++)
      a[mi] = *(const short8*)((const char*)sA + aOff + mi * 1024);
#pragma unroll
    for (int ni = 0; ni < 4; ni++)
      b[ni] = *(const short8*)((const char*)sB + bOff + ni * 1024);
#pragma unroll
    for (int mi = 0; mi < 4; mi++)
#pragma unroll
      for (int ni = 0; ni < 4; ni++)
        acc[mi][ni] = __builtin_amdgcn_mfma_f32_16x16x32_bf16(a[mi], b[ni], acc[mi][ni], 0, 0, 0);
  }

  int l15 = lane & 15;
  int rbase = (lane >> 4) * 4;
  float bias[4];
#pragma unroll
  for (int ni = 0; ni < 4; ni++)
    bias[ni] = B2[p * 1024 + n0 + wn * 64 + ni * 16 + l15];
#pragma unroll
  for (int mi = 0; mi < 4; mi++) {
#pragma unroll
    for (int r = 0; r < 4; r++) {
      int row = r0 + wm * 64 + mi * 16 + rbase + r;
      if (row >= MAXLEN) continue;
      float* dst = RW + ((size_t)p * 240 + row) * 1024 + n0 + wn * 64;
#pragma unroll
      for (int ni = 0; ni < 4; ni++)
        dst[ni * 16 + l15] = acc[mi][ni][r] + bias[ni];
    }
  }
}

__global__ __launch_bounds__(256) void k_hist(const int* __restrict__ tau,
    const int* __restrict__ et, int* __restrict__ cnt) {
  __shared__ int l[32];
  if (threadIdx.x < 32) l[threadIdx.x] = 0;
  __syncthreads();
  int e = blockIdx.x * 256 + threadIdx.x;
  if (e < E_N) atomicAdd(&l[tau[e] * 8 + et[e]], 1);
  __syncthreads();
  if (threadIdx.x < 32) atomicAdd(&cnt[threadIdx.x], l[threadIdx.x]);
}

// c: [0..31]=cnt [32..63]=base(128-aligned) [64..95]=cursor
__global__ void k_bases(int* c) {
  int b = 0;
  for (int p = 0; p < 32; p++) {
    c[32 + p] = b;
    b += ((c[p] + 127) >> 7) << 7;
    c[64 + p] = 0;
  }
}

__global__ __launch_bounds__(256) void k_scatter(const int* __restrict__ tau,
    const int* __restrict__ et, int* __restrict__ c, int* __restrict__ perm) {
  __shared__ int lc[32], lbase[32];
  if (threadIdx.x < 32) lc[threadIdx.x] = 0;
  __syncthreads();
  int e = blockIdx.x * 256 + threadIdx.x;
  bool v = e < E_N;
  int cls = 0, pos = 0;
  if (v) {
    cls = tau[e] * 8 + et[e];
    pos = atomicAdd(&lc[cls], 1);
  }
  __syncthreads();
  if (threadIdx.x < 32) {
    int n = lc[threadIdx.x];
    lbase[threadIdx.x] = (n > 0) ? atomicAdd(&c[64 + threadIdx.x], n) : 0;
  }
  __syncthreads();
  if (v) perm[c[32 + cls] + lbase[cls] + pos] = e;
}

// Fused GEMM, ZERO-LDS ZERO-BARRIER variant: per 128-edge pair-uniform tile,
// C[128][1024] = h_s(bf16) @ W2[p]^T. Each lane loads its MFMA fragments
// DIRECTLY from global (B is bf16 in exact fragment layout; A is f32 rows of
// h_s, converted in-register). No staging, no syncthreads in the k-loop ->
// waves independent, latency hidden by TLP + compiler load hoisting.
// Epilogue adds RW2'[p][dt[e]]; ctile<4 -> att (Q-dot), ctile>=4 -> M f32.
__global__ __launch_bounds__(256, 3) void k_gemm(
    const float* __restrict__ hs, const int* __restrict__ dt,
    const int* __restrict__ tau, const int* __restrict__ et,
    const short* __restrict__ W2, const float* __restrict__ RW,
    const float* __restrict__ Qt, const float* __restrict__ mu,
    const int* __restrict__ perm,
    float* __restrict__ Mout, float* __restrict__ attOut) {
  __shared__ int eRow[128];
  __shared__ int dtRow[128];
  __shared__ int metaP;
  int tid = threadIdx.x;
  // XCD swizzle: 9632 = 8*1204; one ttile's 8 ctiles land on one XCD
  int l = (blockIdx.x & 7) * NTILE2 + (blockIdx.x >> 3);
  int ttile = l >> 3, ctile = l & 7;
  int m0 = ttile * 128;
  if (tid < 128) {
    int e = perm[m0 + tid];
    eRow[tid] = e;
    dtRow[tid] = (e >= 0) ? dt[e] : 0;
  }
  if (tid == 0) {
    int e0 = perm[m0];
    metaP = (e0 >= 0) ? (tau[e0] * 8 + et[e0]) : -1;
  }
  __syncthreads();
  int p = metaP;
  if (p < 0) return;
  int n0 = ctile * 128;

  int lane = tid & 63, w = tid >> 6, wm = w >> 1, wn = w & 1;
  int l15 = lane & 15;
  int kg = lane >> 4;          // k-group 0..3

  // A row base pointers (fragment rows wm*64 + mi*16 + l15), pre-offset by kg*8 floats
  const float* aP[4];
#pragma unroll
  for (int mi = 0; mi < 4; mi++) {
    int e = eRow[wm * 64 + mi * 16 + l15];
    if (e < 0) e = 0;
    aP[mi] = hs + (size_t)e * 512 + kg * 8;
  }
  // B base: row o = p*1024 + n0 + wn*64 + l15 (+ni*16 later), elem kg*8 (+kk*32)
  const short* bP = W2 + ((size_t)p * 1024 + n0 + wn * 64 + l15) * 512 + kg * 8;

  f32x4 acc[4][4] = {};
#pragma unroll 2
  for (int kk = 0; kk < 16; kk++) {
    short8 a[4], b[4];
#pragma unroll
    for (int mi = 0; mi < 4; mi++) {
      float4 f0 = *(const float4*)(aP[mi] + kk * 32);
      float4 f1 = *(const float4*)(aP[mi] + kk * 32 + 4);
      union { short8 s; uint32_t u[4]; } t;
      t.u[0] = pk2(f0.x, f0.y); t.u[1] = pk2(f0.z, f0.w);
      t.u[2] = pk2(f1.x, f1.y); t.u[3] = pk2(f1.z, f1.w);
      a[mi] = t.s;
    }
#pragma unroll
    for (int ni = 0; ni < 4; ni++)
      b[ni] = *(const short8*)(bP + (size_t)ni * 16 * 512 + kk * 32);
#pragma unroll
    for (int mi = 0; mi < 4; mi++)
#pragma unroll
      for (int ni = 0; ni < 4; ni++)
        acc[mi][ni] = __builtin_amdgcn_mfma_f32_16x16x32_bf16(a[mi], b[ni], acc[mi][ni], 0, 0, 0);
  }

  // epilogue
  int rbase = (lane >> 4) * 4;
  if (ctile < 4) {
    int h = ctile * 2 + wn;
    float muv = mu[(p & 7) * 8 + h] * 0.125f;
#pragma unroll
    for (int mi = 0; mi < 4; mi++) {
#pragma unroll
      for (int r = 0; r < 4; r++) {
        int row = wm * 64 + mi * 16 + rbase + r;
        int e = eRow[row];
        if (e < 0) continue;
        const float* rw = RW + ((size_t)p * 240 + dtRow[row]) * 1024 + n0 + wn * 64;
        const float* qp = Qt + (size_t)e * 512 + h * 64;
        float s = 0.f;
#pragma unroll
        for (int ni = 0; ni < 4; ni++)
          s += qp[ni * 16 + l15] * (acc[mi][ni][r] + rw[ni * 16 + l15]);
        s += __shfl_xor(s, 1);
        s += __shfl_xor(s, 2);
        s += __shfl_xor(s, 4);
        s += __shfl_xor(s, 8);
        if (l15 == 0) attOut[(size_t)e * 8 + h] = s * muv;
      }
    }
  } else {
#pragma unroll
    for (int mi = 0; mi < 4; mi++) {
#pragma unroll
      for (int r = 0; r < 4; r++) {
        int row = wm * 64 + mi * 16 + rbase + r;
        int e = eRow[row];
        if (e < 0) continue;
        const float* rw = RW + ((size_t)p * 240 + dtRow[row]) * 1024 + n0 + wn * 64;
        float* md = Mout + (size_t)e * 512 + (n0 - 512) + wn * 64;
#pragma unroll
        for (int ni = 0; ni < 4; ni++)
          md[ni * 16 + l15] = acc[mi][ni][r] + rw[ni * 16 + l15];
      }
    }
  }
}

extern "C" void kernel_launch(void* const* d_in, const int* in_sizes, int n_in,
                              void* d_out, int out_size, void* d_ws, size_t ws_size,
                              hipStream_t stream) {
  const float* hs    = (const float*)d_in[0];
  const float* Qt    = (const float*)d_in[1];
  const int*   et    = (const int*)d_in[2];
  const int*   tau   = (const int*)d_in[3];
  const int*   dt    = (const int*)d_in[4];
  const float* emb   = (const float*)d_in[5];
  const float* linW  = (const float*)d_in[6];
  const float* linB  = (const float*)d_in[7];
  const float* KW    = (const float*)d_in[8];
  const float* Kb    = (const float*)d_in[9];
  const float* VW    = (const float*)d_in[10];
  const float* Vb    = (const float*)d_in[11];
  const float* WattW = (const float*)d_in[12];
  const float* WmsgW = (const float*)d_in[13];
  const float* mu    = (const float*)d_in[14];

  char* ws = (char*)d_ws;
  short* Rbf  = (short*)(ws + OFF_RB);
  short* W2   = (short*)(ws + OFF_W2);
  float* B2   = (float*)(ws + OFF_B2);
  float* RW   = (float*)(ws + OFF_RW);
  int*   cnt  = (int*)(ws + OFF_CNT);
  int*   perm = (int*)(ws + OFF_PERM);

  float* attOut = (float*)d_out;
  float* Mout   = (float*)d_out + (long)E_N * 8;

  hipMemsetAsync(cnt, 0, 128 * sizeof(int), stream);
  hipMemsetAsync(perm, 0xFF, PPERM * sizeof(int), stream);

  k_rte<<<240, 256, 0, stream>>>(emb, linW, linB, Rbf);
  k_wpair<<<2048, 256, 0, stream>>>(WattW, WmsgW, KW, VW, Kb, Vb, W2, B2);
  k_hist<<<(E_N + 255) / 256, 256, 0, stream>>>(tau, et, cnt);
  k_bases<<<1, 1, 0, stream>>>(cnt);
  k_scatter<<<(E_N + 255) / 256, 256, 0, stream>>>(tau, et, cnt, perm);
  k_rw2<<<512, 256, 0, stream>>>(Rbf, W2, B2, RW);
  k_gemm<<<GRID_GEMM, 256, 0, stream>>>(hs, dt, tau, et, W2, RW, Qt, mu, perm, Mout, attOut);
}

// Round 9
// 718.065 us; speedup vs baseline: 1.5777x; 1.5777x over previous
//
#include <hip/hip_runtime.h>
#include <hip/hip_bf16.h>
#include <stdint.h>

#define E_N 150000
#define IN 512
#define MAXLEN 240

// pair-class perm: 32 classes (tau*8+etype), each base 128-aligned
#define PPERM 154112          // >= E + 32*127, multiple of 128
#define NTILE2 1204           // PPERM/128 row-tiles
#define NT_HALF 602           // ttiles per half
#define SLOT_HALF 77056       // NT_HALF*128
#define GRID_GEMM (NT_HALF * 8)

typedef __attribute__((ext_vector_type(8))) short short8;
typedef __attribute__((ext_vector_type(4))) float f32x4;

// ---------- ws layout (bytes) ----------
#define OFF_RF   0UL            // f32  [240][512]        491520
#define OFF_W2   491520UL       // bf16 [32][1024][512]   33554432
#define OFF_B2   34046016UL     // f32  [32][1024]        131072  (64-al)
#define OFF_CNT  34177088UL     // int  [128]             512
#define OFF_PERM 34177600UL     // int  [PPERM]           616448
#define OFF_HH   34794048UL     // bf16 [77056][512]      78905344
// total ~113.7 MB (< 159.5 MB proven)

static __device__ __forceinline__ short f2bf(float f) {
  union { float f; uint32_t u; } v; v.f = f;
  uint32_t u = v.u;
  uint32_t r = (u + 0x7fffu + ((u >> 16) & 1u)) >> 16;
  return (short)r;
}

// R table f32: R[p][o] = sum_i emb[p][i]*linW[o][i] + linB[o]
__global__ __launch_bounds__(256) void k_rte(const float* __restrict__ emb,
    const float* __restrict__ linW, const float* __restrict__ linB,
    float* __restrict__ R) {
  __shared__ float x[IN];
  int p = blockIdx.x;
  for (int i = threadIdx.x; i < IN; i += 256) x[i] = emb[p * IN + i];
  __syncthreads();
  for (int o = threadIdx.x; o < IN; o += 256) {
    const float* w = linW + (long)o * IN;
    float s = 0.f;
#pragma unroll 4
    for (int k = 0; k < IN; k += 4) {
      float4 wv = *(const float4*)(w + k);
      s += wv.x * x[k] + wv.y * x[k + 1] + wv.z * x[k + 2] + wv.w * x[k + 3];
    }
    R[p * IN + o] = s + linB[o];
  }
}

// Pair weights: W2[p=t*8+g][o][i] bf16, B2[p][o] f32.
// grid 2048 = 32 pairs x 16 (8 K-heads + 8 V-heads) x 4 i-quarters
__global__ __launch_bounds__(256) void k_wpair(
    const float* __restrict__ WattW, const float* __restrict__ WmsgW,
    const float* __restrict__ KW, const float* __restrict__ VW,
    const float* __restrict__ Kb, const float* __restrict__ Vb,
    short* __restrict__ W2, float* __restrict__ B2) {
  __shared__ float Tl[64][65];
  int blk = blockIdx.x;
  int p = blk >> 6, s = (blk >> 2) & 15, q = blk & 3;
  int t = p >> 3, g = p & 7;
  bool kside = s < 8;
  int h = kside ? s : s - 8;
  const float* T = (kside ? WattW : WmsgW) + (size_t)g * 4096;
  const float* S = (kside ? KW : VW) + ((size_t)t * 512 + h * 64) * 512;
  const float* bsrc = (kside ? Kb : Vb) + t * 512 + h * 64;
  int tid = threadIdx.x;
  for (int i = tid; i < 4096; i += 256) Tl[i >> 6][i & 63] = T[i];
  __syncthreads();
  int op = tid & 63, iq = tid >> 6;
  size_t obase = ((size_t)p * 1024 + (kside ? 0 : 512) + h * 64 + op) * 512;
  for (int i8 = q * 4; i8 < q * 4 + 4; i8++) {
    int i0 = iq * 128 + i8 * 8;
    float a0 = 0, a1 = 0, a2 = 0, a3 = 0, a4 = 0, a5 = 0, a6 = 0, a7 = 0;
    const float* sp0 = S + i0;
#pragma unroll 8
    for (int j = 0; j < 64; j++) {
      float tv = Tl[op][j];
      const float* sp = sp0 + j * 512;
      float4 s0 = *(const float4*)sp;
      float4 s1 = *(const float4*)(sp + 4);
      a0 += tv * s0.x; a1 += tv * s0.y; a2 += tv * s0.z; a3 += tv * s0.w;
      a4 += tv * s1.x; a5 += tv * s1.y; a6 += tv * s1.z; a7 += tv * s1.w;
    }
    short8 o8;
    o8[0] = f2bf(a0); o8[1] = f2bf(a1); o8[2] = f2bf(a2); o8[3] = f2bf(a3);
    o8[4] = f2bf(a4); o8[5] = f2bf(a5); o8[6] = f2bf(a6); o8[7] = f2bf(a7);
    *(short8*)(W2 + obase + i0) = o8;
  }
  if (q == 0 && tid < 64) {
    float b = 0;
#pragma unroll 8
    for (int j = 0; j < 64; j++) b += Tl[tid][j] * bsrc[j];
    B2[p * 1024 + (kside ? 0 : 512) + h * 64 + tid] = b;
  }
}

__global__ __launch_bounds__(256) void k_hist(const int* __restrict__ tau,
    const int* __restrict__ et, int* __restrict__ cnt) {
  __shared__ int l[32];
  if (threadIdx.x < 32) l[threadIdx.x] = 0;
  __syncthreads();
  int e = blockIdx.x * 256 + threadIdx.x;
  if (e < E_N) atomicAdd(&l[tau[e] * 8 + et[e]], 1);
  __syncthreads();
  if (threadIdx.x < 32) atomicAdd(&cnt[threadIdx.x], l[threadIdx.x]);
}

// c: [0..31]=cnt [32..63]=base(128-aligned) [64..95]=cursor
__global__ void k_bases(int* c) {
  int b = 0;
  for (int p = 0; p < 32; p++) {
    c[32 + p] = b;
    b += ((c[p] + 127) >> 7) << 7;
    c[64 + p] = 0;
  }
}

__global__ __launch_bounds__(256) void k_scatter(const int* __restrict__ tau,
    const int* __restrict__ et, int* __restrict__ c, int* __restrict__ perm) {
  __shared__ int lc[32], lbase[32];
  if (threadIdx.x < 32) lc[threadIdx.x] = 0;
  __syncthreads();
  int e = blockIdx.x * 256 + threadIdx.x;
  bool v = e < E_N;
  int cls = 0, pos = 0;
  if (v) {
    cls = tau[e] * 8 + et[e];
    pos = atomicAdd(&lc[cls], 1);
  }
  __syncthreads();
  if (threadIdx.x < 32) {
    int n = lc[threadIdx.x];
    lbase[threadIdx.x] = (n > 0) ? atomicAdd(&c[64 + threadIdx.x], n) : 0;
  }
  __syncthreads();
  if (v) perm[c[32 + cls] + lbase[cls] + pos] = e;
}

// h_hat in PERM ORDER (dense slots): Hh[local] = bf16(hs[perm[slot0+local]] + R[dt[e]])
// 16 rows/block, 16 threads/row (32 floats each). Pad slots -> zeros.
__global__ __launch_bounds__(256) void k_hhat(const float* __restrict__ hs,
    const float* __restrict__ R, const int* __restrict__ dt,
    const int* __restrict__ perm, int slot0, short* __restrict__ Hh) {
  int tid = threadIdx.x;
  int local = blockIdx.x * 16 + (tid >> 4);
  int e = perm[slot0 + local];
  int sub = tid & 15;
  short* op = Hh + (size_t)local * 512 + sub * 32;
  if (e < 0) {
    short8 z = {};
#pragma unroll
    for (int j = 0; j < 4; j++) *(short8*)(op + j * 8) = z;
    return;
  }
  const float* hp = hs + (size_t)e * 512 + sub * 32;
  const float* rp = R + (size_t)dt[e] * 512 + sub * 32;
#pragma unroll
  for (int j = 0; j < 4; j++) {
    float4 h0 = *(const float4*)(hp + j * 8);
    float4 h1 = *(const float4*)(hp + j * 8 + 4);
    float4 r0 = *(const float4*)(rp + j * 8);
    float4 r1 = *(const float4*)(rp + j * 8 + 4);
    short8 o;
    o[0] = f2bf(h0.x + r0.x); o[1] = f2bf(h0.y + r0.y);
    o[2] = f2bf(h0.z + r0.z); o[3] = f2bf(h0.w + r0.w);
    o[4] = f2bf(h1.x + r1.x); o[5] = f2bf(h1.y + r1.y);
    o[6] = f2bf(h1.z + r1.z); o[7] = f2bf(h1.w + r1.w);
    *(short8*)(op + j * 8) = o;
  }
}

// Fused GEMM, round-3 proven structure: per 128-slot pair-uniform tile,
// C[128][1024] = Hh(bf16,dense) @ W2[p]^T + B2. Both operands via
// global_load_lds + chunk swizzle (0-conflict), plain 2-barrier k-loop.
// ctile<4 -> att (Q-dot + mu/8), ctile>=4 -> M f32 direct to d_out.
__global__ __launch_bounds__(256, 4) void k_gemm(
    const short* __restrict__ Hh, const int* __restrict__ tau,
    const int* __restrict__ et,
    const short* __restrict__ W2, const float* __restrict__ B2,
    const float* __restrict__ Qt, const float* __restrict__ mu,
    const int* __restrict__ perm, int ttile0,
    float* __restrict__ Mout, float* __restrict__ attOut) {
  __shared__ short sA[4096];   // [128 rows][32 k] bf16, chunk-swizzled
  __shared__ short sB[4096];
  __shared__ int eRow[128];
  __shared__ int metaP;
  int tid = threadIdx.x;
  // XCD swizzle: 4816 = 8*602; contiguous l-chunk per XCD
  int l = (blockIdx.x & 7) * NT_HALF + (blockIdx.x >> 3);
  int tloc = l >> 3, ctile = l & 7;
  int m0 = (ttile0 + tloc) * 128;    // global slot base (perm index)
  if (tid < 128) eRow[tid] = perm[m0 + tid];
  if (tid == 0) {
    int e0 = perm[m0];
    metaP = (e0 >= 0) ? (tau[e0] * 8 + et[e0]) : -1;
  }
  __syncthreads();
  int p = metaP;
  if (p < 0) return;
  int n0 = ctile * 128;

  int lane = tid & 63, w = tid >> 6, wm = w >> 1, wn = w & 1;

  // staging: wave w stages rows [w*32, w*32+32)
  int rS = w * 32 + (lane >> 2);
  int cS = lane & 3;
  int ch0 = (cS - (rS >> 1)) & 3;          // inverse swizzle -> source chunk
  int ch1 = (cS - ((rS + 16) >> 1)) & 3;
  const char* hbase = (const char*)Hh + (size_t)tloc * 128 * 1024;  // dense!
  const char* srcA0 = hbase + (size_t)rS * 1024 + ch0 * 16;
  const char* srcA1 = hbase + (size_t)(rS + 16) * 1024 + ch1 * 16;
  const char* wcb = (const char*)(W2 + ((size_t)p * 1024 + n0) * 512);
  const char* srcB0 = wcb + (size_t)rS * 1024 + ch0 * 16;
  const char* srcB1 = wcb + (size_t)(rS + 16) * 1024 + ch1 * 16;
  char* dA0 = (char*)sA + w * 2048;
  char* dA1 = (char*)sA + w * 2048 + 1024;
  char* dB0 = (char*)sB + w * 2048;
  char* dB1 = (char*)sB + w * 2048 + 1024;

  // fragment read bases (chunk-swizzled)
  int aRow = wm * 64 + (lane & 15);
  int aOff = aRow * 64 + ((((lane >> 4) + (aRow >> 1)) & 3) << 4);
  int bRow = wn * 64 + (lane & 15);
  int bOff = bRow * 64 + ((((lane >> 4) + (bRow >> 1)) & 3) << 4);

  f32x4 acc[4][4] = {};
#pragma unroll
  for (int kk = 0; kk < 16; kk++) {
    __syncthreads();   // previous iter's reads done before overwrite
    __builtin_amdgcn_global_load_lds((const uint32_t*)(srcA0 + kk * 64), (uint32_t*)dA0, 16, 0, 0);
    __builtin_amdgcn_global_load_lds((const uint32_t*)(srcA1 + kk * 64), (uint32_t*)dA1, 16, 0, 0);
    __builtin_amdgcn_global_load_lds((const uint32_t*)(srcB0 + kk * 64), (uint32_t*)dB0, 16, 0, 0);
    __builtin_amdgcn_global_load_lds((const uint32_t*)(srcB1 + kk * 64), (uint32_t*)dB1, 16, 0, 0);
    __syncthreads();   // compiler drains vmcnt(0) before barrier
    short8 a[4], b[4];
#pragma unroll
    for (int mi = 0; mi < 4; mi++)
      a[mi] = *(const short8*)((const char*)sA + aOff + mi * 1024);
#pragma unroll
    for (int ni = 0; ni < 4; ni++)
      b[ni] = *(const short8*)((const char*)sB + bOff + ni * 1024);
#pragma unroll
    for (int mi = 0; mi < 4; mi++)
#pragma unroll
      for (int ni = 0; ni < 4; ni++)
        acc[mi][ni] = __builtin_amdgcn_mfma_f32_16x16x32_bf16(a[mi], b[ni], acc[mi][ni], 0, 0, 0);
  }

  // epilogue: D row=(lane>>4)*4+reg (A-row), col=lane&15 (B-col)
  int l15 = lane & 15;
  int rbase = (lane >> 4) * 4;
  float bias[4];
#pragma unroll
  for (int ni = 0; ni < 4; ni++)
    bias[ni] = B2[p * 1024 + n0 + wn * 64 + ni * 16 + l15];
  if (ctile < 4) {
    int h = ctile * 2 + wn;
    float muv = mu[(p & 7) * 8 + h] * 0.125f;
#pragma unroll
    for (int mi = 0; mi < 4; mi++) {
#pragma unroll
      for (int r = 0; r < 4; r++) {
        int row = wm * 64 + mi * 16 + rbase + r;
        int e = eRow[row];
        if (e < 0) continue;
        const float* qp = Qt + (size_t)e * 512 + h * 64;
        float s = 0.f;
#pragma unroll
        for (int ni = 0; ni < 4; ni++)
          s += qp[ni * 16 + l15] * (acc[mi][ni][r] + bias[ni]);
        s += __shfl_xor(s, 1);
        s += __shfl_xor(s, 2);
        s += __shfl_xor(s, 4);
        s += __shfl_xor(s, 8);
        if (l15 == 0) attOut[(size_t)e * 8 + h] = s * muv;
      }
    }
  } else {
#pragma unroll
    for (int mi = 0; mi < 4; mi++) {
#pragma unroll
      for (int r = 0; r < 4; r++) {
        int row = wm * 64 + mi * 16 + rbase + r;
        int e = eRow[row];
        if (e < 0) continue;
        float* md = Mout + (size_t)e * 512 + (n0 - 512) + wn * 64;
#pragma unroll
        for (int ni = 0; ni < 4; ni++)
          md[ni * 16 + l15] = acc[mi][ni][r] + bias[ni];
      }
    }
  }
}

extern "C" void kernel_launch(void* const* d_in, const int* in_sizes, int n_in,
                              void* d_out, int out_size, void* d_ws, size_t ws_size,
                              hipStream_t stream) {
  const float* hs    = (const float*)d_in[0];
  const float* Qt    = (const float*)d_in[1];
  const int*   et    = (const int*)d_in[2];
  const int*   tau   = (const int*)d_in[3];
  const int*   dt    = (const int*)d_in[4];
  const float* emb   = (const float*)d_in[5];
  const float* linW  = (const float*)d_in[6];
  const float* linB  = (const float*)d_in[7];
  const float* KW    = (const float*)d_in[8];
  const float* Kb    = (const float*)d_in[9];
  const float* VW    = (const float*)d_in[10];
  const float* Vb    = (const float*)d_in[11];
  const float* WattW = (const float*)d_in[12];
  const float* WmsgW = (const float*)d_in[13];
  const float* mu    = (const float*)d_in[14];

  char* ws = (char*)d_ws;
  float* Rf   = (float*)(ws + OFF_RF);
  short* W2   = (short*)(ws + OFF_W2);
  float* B2   = (float*)(ws + OFF_B2);
  int*   cnt  = (int*)(ws + OFF_CNT);
  int*   perm = (int*)(ws + OFF_PERM);
  short* Hh   = (short*)(ws + OFF_HH);

  float* attOut = (float*)d_out;
  float* Mout   = (float*)d_out + (long)E_N * 8;

  hipMemsetAsync(cnt, 0, 128 * sizeof(int), stream);
  hipMemsetAsync(perm, 0xFF, PPERM * sizeof(int), stream);

  k_rte<<<240, 256, 0, stream>>>(emb, linW, linB, Rf);
  k_wpair<<<2048, 256, 0, stream>>>(WattW, WmsgW, KW, VW, Kb, Vb, W2, B2);
  k_hist<<<(E_N + 255) / 256, 256, 0, stream>>>(tau, et, cnt);
  k_bases<<<1, 1, 0, stream>>>(cnt);
  k_scatter<<<(E_N + 255) / 256, 256, 0, stream>>>(tau, et, cnt, perm);

  // half 0
  k_hhat<<<SLOT_HALF / 16, 256, 0, stream>>>(hs, Rf, dt, perm, 0, Hh);
  k_gemm<<<GRID_GEMM, 256, 0, stream>>>(Hh, tau, et, W2, B2, Qt, mu, perm, 0, Mout, attOut);
  // half 1
  k_hhat<<<SLOT_HALF / 16, 256, 0, stream>>>(hs, Rf, dt, perm, SLOT_HALF, Hh);
  k_gemm<<<GRID_GEMM, 256, 0, stream>>>(Hh, tau, et, W2, B2, Qt, mu, perm, NT_HALF, Mout, attOut);
}